// Round 6
// baseline (2478.859 us; speedup 1.0000x reference)
//
#include <hip/hip_runtime.h>

#define INC 256
#define HD 128
#define ZD 64
#define NPB 196   // nodes per bucket (196*128*4B = 100KB LDS accumulator)
#define NB  256   // buckets = ceil(50000/196)

typedef __attribute__((ext_vector_type(8))) short bf16x8;
typedef __attribute__((ext_vector_type(4))) float f32x4;

static __device__ __forceinline__ unsigned short f2b(float f) {
    unsigned u = __builtin_bit_cast(unsigned, f);
    unsigned r = (u + 0x7fffu + ((u >> 16) & 1u)) >> 16;  // RNE
    return (unsigned short)r;
}
static __device__ __forceinline__ float b_lo(unsigned u) {
    return __builtin_bit_cast(float, u << 16);
}
static __device__ __forceinline__ float b_hi(unsigned u) {
    return __builtin_bit_cast(float, u & 0xffff0000u);
}

// ---------------- degree + dinv ----------------

__global__ void k_count(const int* __restrict__ dst, int* __restrict__ cnt, int E) {
    int i = blockIdx.x * blockDim.x + threadIdx.x;
    if (i < E) atomicAdd(&cnt[dst[i]], 1);
}

__global__ void k_dinv(const int* __restrict__ cnt, float* __restrict__ dinv, int n) {
    int i = blockIdx.x * blockDim.x + threadIdx.x;
    if (i < n) dinv[i] = rsqrtf((float)(cnt[i] + 1));  // +1 self-loop
}

// ---------------- bucket histogram / scan / pair scatter ----------------

__global__ __launch_bounds__(256) void k_bhist(const int* __restrict__ dst,
                                               int* __restrict__ bhist, int E) {
    __shared__ int h[NB];
    h[threadIdx.x] = 0;
    __syncthreads();
    for (int i = blockIdx.x * blockDim.x + threadIdx.x; i < E; i += gridDim.x * blockDim.x)
        atomicAdd(&h[dst[i] / NPB], 1);
    __syncthreads();
    int v = h[threadIdx.x];
    if (v) atomicAdd(&bhist[threadIdx.x], v);
}

__global__ __launch_bounds__(NB) void k_bscan(const int* __restrict__ bhist,
                                              int* __restrict__ bbase,
                                              int* __restrict__ bcur) {
    __shared__ int s[NB];
    int t = threadIdx.x;
    int v = bhist[t];
    s[t] = v;
    __syncthreads();
    for (int o = 1; o < NB; o <<= 1) {
        int x = (t >= o) ? s[t - o] : 0;
        __syncthreads();
        s[t] += x;
        __syncthreads();
    }
    bbase[t] = s[t] - v;
    bcur[t] = s[t] - v;
}

// block handles 1024 edges; rank within bucket via LDS, reserve range, write pairs
__global__ __launch_bounds__(256) void k_bscatter(const int* __restrict__ src,
                                                  const int* __restrict__ dst,
                                                  int* __restrict__ bcur,
                                                  uint2* __restrict__ pair, int E) {
    __shared__ int lcnt[NB];
    __shared__ int lbase[NB];
    const int t = threadIdx.x;
    lcnt[t] = 0;
    __syncthreads();
    const int c0 = blockIdx.x * 1024;
    int s_[4], d_[4], r_[4], b_[4], m_ = 0;
#pragma unroll
    for (int k = 0; k < 4; k++) {
        int i = c0 + k * 256 + t;
        if (i < E) {
            int dd = dst[i];
            int b = dd / NPB;
            s_[k] = src[i]; d_[k] = dd; b_[k] = b;
            r_[k] = atomicAdd(&lcnt[b], 1);
            m_ = k + 1;
        }
    }
    __syncthreads();
    lbase[t] = lcnt[t] ? atomicAdd(&bcur[t], lcnt[t]) : 0;
    __syncthreads();
    for (int k = 0; k < m_; k++)
        pair[lbase[b_[k]] + r_[k]] = make_uint2((unsigned)s_[k], (unsigned)d_[k]);
}

// ---------------- W pack: [K][128] f32 -> MFMA B-fragment-major bf16 ----------

template <int K, int SPLITB>
__global__ void k_pack(const float* __restrict__ Wa, const float* __restrict__ Wb,
                       unsigned short* __restrict__ Wp) {
    int idx = blockIdx.x * 256 + threadIdx.x;  // < K*128
    int j = idx & 7, lane = (idx >> 3) & 63, c = (idx >> 9) & 7, s = idx >> 12;
    int k = s * 32 + (lane >> 4) * 8 + j;
    int col = c * 16 + (lane & 15);
    float v;
    if (!SPLITB) v = Wa[k * 128 + col];
    else v = (col < 64) ? Wa[k * 64 + col] : Wb[k * 64 + (col - 64)];
    Wp[idx] = f2b(v);
}

// ---------------- MFMA GEMM: Y[n,128](bf16) = A[n,K] @ Wp ----------------
// AF32: A loaded from f32 and converted in-register (fused cast)

template <int K, int AF32>
__global__ __launch_bounds__(256) void k_mgemm(const void* __restrict__ Av,
                                               const unsigned short* __restrict__ Wp,
                                               unsigned short* __restrict__ Y, int n) {
    const int lane = threadIdx.x & 63;
    const int w = threadIdx.x >> 6;
    const int rowbase = blockIdx.x * 64 + w * 16;
    int arow = rowbase + (lane & 15);
    if (arow >= n) arow = n - 1;  // clamp; stores are guarded
    const int kgrp = lane >> 4;

    f32x4 acc[8] = {};
#pragma unroll
    for (int s = 0; s < K / 32; s++) {
        bf16x8 a;
        if (AF32) {
            const float* ap = (const float*)Av + (size_t)arow * K + s * 32 + kgrp * 8;
            float4 f0 = *reinterpret_cast<const float4*>(ap);
            float4 f1 = *reinterpret_cast<const float4*>(ap + 4);
            a[0] = (short)f2b(f0.x); a[1] = (short)f2b(f0.y);
            a[2] = (short)f2b(f0.z); a[3] = (short)f2b(f0.w);
            a[4] = (short)f2b(f1.x); a[5] = (short)f2b(f1.y);
            a[6] = (short)f2b(f1.z); a[7] = (short)f2b(f1.w);
        } else {
            a = *reinterpret_cast<const bf16x8*>((const unsigned short*)Av +
                                                 (size_t)arow * K + s * 32 + kgrp * 8);
        }
        const bf16x8* bp = reinterpret_cast<const bf16x8*>(Wp) + ((size_t)s * 8 * 64 + lane);
#pragma unroll
        for (int c = 0; c < 8; c++) {
            bf16x8 b = bp[c * 64];
            acc[c] = __builtin_amdgcn_mfma_f32_16x16x32_bf16(a, b, acc[c], 0, 0, 0);
        }
    }
    const int r0 = rowbase + (lane >> 4) * 4;
    const int col = lane & 15;
#pragma unroll
    for (int c = 0; c < 8; c++) {
#pragma unroll
        for (int r = 0; r < 4; r++) {
            int rr = r0 + r;
            if (rr < n) Y[(size_t)rr * 128 + c * 16 + col] = f2b(acc[c][r]);
        }
    }
}

// ---------------- bucketed aggregation ----------------
// block = bucket: LDS f32 acc[196][128]; per edge: broadcast (src,dst,dinv),
// gather 256B row, ds_add_f32. Lane covers cols {l, 64+l} in the accumulate
// phase (4B-stride across lanes -> conflict-free ds_add), {2l, 2l+1} at writeout.

template <int RELU, int SPLIT>
__global__ __launch_bounds__(1024) void k_agg_b(const unsigned* __restrict__ in,
                                                const uint2* __restrict__ pair,
                                                const int* __restrict__ bbase,
                                                const int* __restrict__ bhist,
                                                const float* __restrict__ dinv,
                                                const float* __restrict__ b0,
                                                const float* __restrict__ b1,
                                                void* __restrict__ out0v,
                                                void* __restrict__ out1v, int n) {
    __shared__ float acc[NPB * 128];
    const int t = threadIdx.x;
    const int lane = t & 63;
    const int w = t >> 6;  // 0..15
    const int node0 = blockIdx.x * NPB;

    for (int i = t; i < NPB * 128; i += 1024) acc[i] = 0.f;
    __syncthreads();

    const int lo = bbase[blockIdx.x];
    const int hi = lo + bhist[blockIdx.x];
    const int hw = lane >> 1;          // uint index within row
    const int odd = lane & 1;

    for (int be = lo + w * 64; be < hi; be += 16 * 64) {
        int rem = hi - be;
        int jm = rem < 64 ? rem : 64;
        uint2 pr = (lane < jm) ? pair[be + lane] : make_uint2(0u, (unsigned)node0);
        float dv = (lane < jm) ? dinv[pr.x] : 0.f;
        int j = 0;
        for (; j + 3 < jm; j += 4) {
            int s0 = __shfl((int)pr.x, j),     t0 = __shfl((int)pr.y, j);     float v0 = __shfl(dv, j);
            int s1 = __shfl((int)pr.x, j + 1), t1 = __shfl((int)pr.y, j + 1); float v1 = __shfl(dv, j + 1);
            int s2 = __shfl((int)pr.x, j + 2), t2 = __shfl((int)pr.y, j + 2); float v2 = __shfl(dv, j + 2);
            int s3 = __shfl((int)pr.x, j + 3), t3 = __shfl((int)pr.y, j + 3); float v3 = __shfl(dv, j + 3);
            unsigned ua0 = in[(size_t)s0 * 64 + hw], ub0 = in[(size_t)s0 * 64 + 32 + hw];
            unsigned ua1 = in[(size_t)s1 * 64 + hw], ub1 = in[(size_t)s1 * 64 + 32 + hw];
            unsigned ua2 = in[(size_t)s2 * 64 + hw], ub2 = in[(size_t)s2 * 64 + 32 + hw];
            unsigned ua3 = in[(size_t)s3 * 64 + hw], ub3 = in[(size_t)s3 * 64 + 32 + hw];
            float* a0 = &acc[(t0 - node0) * 128 + lane];
            atomicAdd(a0,      v0 * (odd ? b_hi(ua0) : b_lo(ua0)));
            atomicAdd(a0 + 64, v0 * (odd ? b_hi(ub0) : b_lo(ub0)));
            float* a1 = &acc[(t1 - node0) * 128 + lane];
            atomicAdd(a1,      v1 * (odd ? b_hi(ua1) : b_lo(ua1)));
            atomicAdd(a1 + 64, v1 * (odd ? b_hi(ub1) : b_lo(ub1)));
            float* a2 = &acc[(t2 - node0) * 128 + lane];
            atomicAdd(a2,      v2 * (odd ? b_hi(ua2) : b_lo(ua2)));
            atomicAdd(a2 + 64, v2 * (odd ? b_hi(ub2) : b_lo(ub2)));
            float* a3 = &acc[(t3 - node0) * 128 + lane];
            atomicAdd(a3,      v3 * (odd ? b_hi(ua3) : b_lo(ua3)));
            atomicAdd(a3 + 64, v3 * (odd ? b_hi(ub3) : b_lo(ub3)));
        }
        for (; j < jm; j++) {
            int s0 = __shfl((int)pr.x, j), t0 = __shfl((int)pr.y, j);
            float v0 = __shfl(dv, j);
            unsigned ua0 = in[(size_t)s0 * 64 + hw], ub0 = in[(size_t)s0 * 64 + 32 + hw];
            float* a0 = &acc[(t0 - node0) * 128 + lane];
            atomicAdd(a0,      v0 * (odd ? b_hi(ua0) : b_lo(ua0)));
            atomicAdd(a0 + 64, v0 * (odd ? b_hi(ub0) : b_lo(ub0)));
        }
    }
    __syncthreads();

    // writeout: lane covers cols {2l, 2l+1}
    const int npa = min(NPB, n - node0);
    for (int r = w; r < npa; r += 16) {
        int d = node0 + r;
        float dd = dinv[d];
        unsigned su = in[(size_t)d * 64 + lane];
        float ax = dd * acc[r * 128 + lane * 2]     + dd * dd * b_lo(su);
        float ay = dd * acc[r * 128 + lane * 2 + 1] + dd * dd * b_hi(su);
        if (!SPLIT) {
            float2 bb = reinterpret_cast<const float2*>(b0)[lane];
            ax += bb.x; ay += bb.y;
            if (RELU) { ax = fmaxf(ax, 0.f); ay = fmaxf(ay, 0.f); }
            ((unsigned*)out0v)[(size_t)d * 64 + lane] =
                (unsigned)f2b(ax) | ((unsigned)f2b(ay) << 16);
        } else {
            if (lane < 32) {
                float2 bb = reinterpret_cast<const float2*>(b0)[lane];
                reinterpret_cast<float2*>(out0v)[(size_t)d * 32 + lane] =
                    make_float2(ax + bb.x, ay + bb.y);
            } else {
                float2 bb = reinterpret_cast<const float2*>(b1)[lane - 32];
                reinterpret_cast<float2*>(out1v)[(size_t)d * 32 + (lane - 32)] =
                    make_float2(ax + bb.x, ay + bb.y);
            }
        }
    }
}

// ---------------- launch ----------------

extern "C" void kernel_launch(void* const* d_in, const int* in_sizes, int n_in,
                              void* d_out, int out_size, void* d_ws, size_t ws_size,
                              hipStream_t stream) {
    const float* x    = (const float*)d_in[0];
    const float* W_h  = (const float*)d_in[1];
    const float* b_h  = (const float*)d_in[2];
    const float* W_mu = (const float*)d_in[3];
    const float* b_mu = (const float*)d_in[4];
    const float* W_ls = (const float*)d_in[5];
    const float* b_ls = (const float*)d_in[6];
    const int*   ei   = (const int*)d_in[7];

    const int E = in_sizes[7] / 2;
    const int n = in_sizes[0] / INC;  // 50000
    const int* src = ei;
    const int* dst = ei + E;
    float* out = (float*)d_out;

    char* p = (char*)d_ws;
    auto carve = [&](size_t bytes) {
        void* r = (void*)p;
        p += (bytes + 255) & ~(size_t)255;
        return r;
    };
    unsigned short* xw  = (unsigned short*)carve((size_t)n * HD * 2);   // gemm out (both layers)
    unsigned short* h   = (unsigned short*)carve((size_t)n * HD * 2);   // agg1 out
    unsigned short* wp1 = (unsigned short*)carve((size_t)INC * HD * 2);
    unsigned short* wp2 = (unsigned short*)carve((size_t)HD * HD * 2);
    float* dinv  = (float*)carve((size_t)n * 4);
    int*   cnt   = (int*)carve((size_t)n * 4);
    int*   bhist = (int*)carve((size_t)NB * 4);
    int*   bbase = (int*)carve((size_t)NB * 4);
    int*   bcur  = (int*)carve((size_t)NB * 4);
    uint2* pair  = (uint2*)carve((size_t)E * 8);

    hipMemsetAsync(cnt, 0, (size_t)n * 4, stream);
    hipMemsetAsync(bhist, 0, (size_t)NB * 4, stream);

    k_count<<<(E + 255) / 256, 256, 0, stream>>>(dst, cnt, E);
    k_dinv<<<(n + 255) / 256, 256, 0, stream>>>(cnt, dinv, n);
    k_bhist<<<256, 256, 0, stream>>>(dst, bhist, E);
    k_bscan<<<1, NB, 0, stream>>>(bhist, bbase, bcur);
    k_bscatter<<<(E + 1023) / 1024, 256, 0, stream>>>(src, dst, bcur, pair, E);

    k_pack<INC, 0><<<INC * HD / 256, 256, 0, stream>>>(W_h, nullptr, wp1);
    k_pack<HD, 1><<<HD * HD / 256, 256, 0, stream>>>(W_mu, W_ls, wp2);

    const int nbk = (n + NPB - 1) / NPB;  // 256
    k_mgemm<INC, 1><<<(n + 63) / 64, 256, 0, stream>>>(x, wp1, xw, n);
    k_agg_b<1, 0><<<nbk, 1024, 0, stream>>>((const unsigned*)xw, pair, bbase, bhist,
                                            dinv, b_h, nullptr, h, nullptr, n);
    k_mgemm<HD, 0><<<(n + 63) / 64, 256, 0, stream>>>(h, wp2, xw, n);
    k_agg_b<0, 1><<<nbk, 1024, 0, stream>>>((const unsigned*)xw, pair, bbase, bhist,
                                            dinv, b_mu, b_ls, out, out + (size_t)n * ZD, n);
}

// Round 9
// 409.576 us; speedup vs baseline: 6.0523x; 6.0523x over previous
//
#include <hip/hip_runtime.h>

#define INC 256
#define HD 128
#define ZD 64
#define SBS 256
#define NPB 196   // nodes per bucket
#define NB  256   // buckets = ceil(50000/196)

typedef __attribute__((ext_vector_type(8))) short bf16x8;
typedef __attribute__((ext_vector_type(4))) float f32x4;

static __device__ __forceinline__ unsigned short f2b(float f) {
    unsigned u = __builtin_bit_cast(unsigned, f);
    unsigned r = (u + 0x7fffu + ((u >> 16) & 1u)) >> 16;  // RNE
    return (unsigned short)r;
}
static __device__ __forceinline__ float b_lo(unsigned u) {
    return __builtin_bit_cast(float, u << 16);
}
static __device__ __forceinline__ float b_hi(unsigned u) {
    return __builtin_bit_cast(float, u & 0xffff0000u);
}

// ---------------- degree + dinv ----------------

__global__ void k_count(const int* __restrict__ dst, int* __restrict__ cnt, int E) {
    int i = blockIdx.x * blockDim.x + threadIdx.x;
    if (i < E) atomicAdd(&cnt[dst[i]], 1);
}

__global__ void k_dinv(const int* __restrict__ cnt, float* __restrict__ dinv, int n) {
    int i = blockIdx.x * blockDim.x + threadIdx.x;
    if (i < n) dinv[i] = rsqrtf((float)(cnt[i] + 1));  // +1 self-loop
}

// ---------------- rowstart scan (3 kernels, cheap) ----------------

__global__ void k_scan1(const int* __restrict__ cnt, int* __restrict__ part, int n) {
    __shared__ int s[SBS];
    int i = blockIdx.x * SBS + threadIdx.x;
    s[threadIdx.x] = (i < n) ? cnt[i] : 0;
    __syncthreads();
    for (int o = SBS / 2; o > 0; o >>= 1) {
        if (threadIdx.x < o) s[threadIdx.x] += s[threadIdx.x + o];
        __syncthreads();
    }
    if (threadIdx.x == 0) part[blockIdx.x] = s[0];
}

__global__ void k_scan2(int* __restrict__ part, int nb) {
    __shared__ int s[SBS];
    int t = threadIdx.x;
    int v = (t < nb) ? part[t] : 0;
    s[t] = v;
    __syncthreads();
    for (int o = 1; o < SBS; o <<= 1) {
        int x = (t >= o) ? s[t - o] : 0;
        __syncthreads();
        s[t] += x;
        __syncthreads();
    }
    if (t < nb) part[t] = s[t] - v;  // exclusive
}

__global__ void k_scan3(const int* __restrict__ cnt, const int* __restrict__ part,
                        int* __restrict__ rowstart, int n) {
    __shared__ int s[SBS];
    int t = threadIdx.x;
    int i = blockIdx.x * SBS + t;
    int v = (i < n) ? cnt[i] : 0;
    s[t] = v;
    __syncthreads();
    for (int o = 1; o < SBS; o <<= 1) {
        int x = (t >= o) ? s[t - o] : 0;
        __syncthreads();
        s[t] += x;
        __syncthreads();
    }
    if (i < n) rowstart[i] = part[blockIdx.x] + s[t] - v;
}

// ---------------- bucket histogram / scan / packed pair scatter ----------------

__global__ __launch_bounds__(256) void k_bhist(const int* __restrict__ dst,
                                               int* __restrict__ bhist, int E) {
    __shared__ int h[NB];
    h[threadIdx.x] = 0;
    __syncthreads();
    for (int i = blockIdx.x * blockDim.x + threadIdx.x; i < E; i += gridDim.x * blockDim.x)
        atomicAdd(&h[dst[i] / NPB], 1);
    __syncthreads();
    int v = h[threadIdx.x];
    if (v) atomicAdd(&bhist[threadIdx.x], v);
}

__global__ __launch_bounds__(NB) void k_bscan(const int* __restrict__ bhist,
                                              int* __restrict__ bbase,
                                              int* __restrict__ bcur) {
    __shared__ int s[NB];
    int t = threadIdx.x;
    int v = bhist[t];
    s[t] = v;
    __syncthreads();
    for (int o = 1; o < NB; o <<= 1) {
        int x = (t >= o) ? s[t - o] : 0;
        __syncthreads();
        s[t] += x;
        __syncthreads();
    }
    bbase[t] = s[t] - v;
    bcur[t] = s[t] - v;
}

// block handles 1024 edges; rank within bucket via LDS, reserve range, write
// packed (local_dst<<16 | src) -- valid because src < 50000 < 65536.
__global__ __launch_bounds__(256) void k_bscatter(const int* __restrict__ src,
                                                  const int* __restrict__ dst,
                                                  int* __restrict__ bcur,
                                                  unsigned* __restrict__ pairp, int E) {
    __shared__ int lcnt[NB];
    __shared__ int lbase[NB];
    const int t = threadIdx.x;
    lcnt[t] = 0;
    __syncthreads();
    const int c0 = blockIdx.x * 1024;
    unsigned u_[4]; int r_[4], b_[4], m_ = 0;
#pragma unroll
    for (int k = 0; k < 4; k++) {
        int i = c0 + k * 256 + t;
        if (i < E) {
            int dd = dst[i];
            int b = dd / NPB;
            b_[k] = b;
            u_[k] = (unsigned)src[i] | ((unsigned)(dd - b * NPB) << 16);
            r_[k] = atomicAdd(&lcnt[b], 1);
            m_ = k + 1;
        }
    }
    __syncthreads();
    lbase[t] = lcnt[t] ? atomicAdd(&bcur[t], lcnt[t]) : 0;
    __syncthreads();
    for (int k = 0; k < m_; k++)
        pairp[lbase[b_[k]] + r_[k]] = u_[k];
}

// per-bucket exact-CSR placement; write window = bucket's 25KB CSR slice (L2-combined)
__global__ __launch_bounds__(256) void k_csr(const unsigned* __restrict__ pairp,
                                             const int* __restrict__ bbase,
                                             const int* __restrict__ bhist,
                                             const int* __restrict__ rowstart,
                                             int* __restrict__ csr, int n) {
    __shared__ int cur[NPB];
    const int b = blockIdx.x;
    const int node0 = b * NPB;
    const int np = min(NPB, n - node0);
    for (int r = threadIdx.x; r < np; r += 256) cur[r] = rowstart[node0 + r];
    __syncthreads();
    const int lo = bbase[b], hi = lo + bhist[b];
    for (int i = lo + threadIdx.x; i < hi; i += 256) {
        unsigned u = pairp[i];
        int p = atomicAdd(&cur[u >> 16], 1);
        csr[p] = (int)(u & 0xffffu);
    }
}

// ---------------- W pack: [K][128] f32 -> MFMA B-fragment-major bf16 ----------

template <int K, int SPLITB>
__global__ void k_pack(const float* __restrict__ Wa, const float* __restrict__ Wb,
                       unsigned short* __restrict__ Wp) {
    int idx = blockIdx.x * 256 + threadIdx.x;  // < K*128
    int j = idx & 7, lane = (idx >> 3) & 63, c = (idx >> 9) & 7, s = idx >> 12;
    int k = s * 32 + (lane >> 4) * 8 + j;
    int col = c * 16 + (lane & 15);
    float v;
    if (!SPLITB) v = Wa[k * 128 + col];
    else v = (col < 64) ? Wa[k * 64 + col] : Wb[k * 64 + (col - 64)];
    Wp[idx] = f2b(v);
}

// ---------------- MFMA GEMM: Y[n,128](bf16) = A[n,K] @ Wp ----------------

template <int K, int AF32>
__global__ __launch_bounds__(256) void k_mgemm(const void* __restrict__ Av,
                                               const unsigned short* __restrict__ Wp,
                                               unsigned short* __restrict__ Y, int n) {
    const int lane = threadIdx.x & 63;
    const int w = threadIdx.x >> 6;
    const int rowbase = blockIdx.x * 64 + w * 16;
    int arow = rowbase + (lane & 15);
    if (arow >= n) arow = n - 1;  // clamp; stores are guarded
    const int kgrp = lane >> 4;

    f32x4 acc[8] = {};
#pragma unroll
    for (int s = 0; s < K / 32; s++) {
        bf16x8 a;
        if (AF32) {
            const float* ap = (const float*)Av + (size_t)arow * K + s * 32 + kgrp * 8;
            float4 f0 = *reinterpret_cast<const float4*>(ap);
            float4 f1 = *reinterpret_cast<const float4*>(ap + 4);
            a[0] = (short)f2b(f0.x); a[1] = (short)f2b(f0.y);
            a[2] = (short)f2b(f0.z); a[3] = (short)f2b(f0.w);
            a[4] = (short)f2b(f1.x); a[5] = (short)f2b(f1.y);
            a[6] = (short)f2b(f1.z); a[7] = (short)f2b(f1.w);
        } else {
            a = *reinterpret_cast<const bf16x8*>((const unsigned short*)Av +
                                                 (size_t)arow * K + s * 32 + kgrp * 8);
        }
        const bf16x8* bp = reinterpret_cast<const bf16x8*>(Wp) + ((size_t)s * 8 * 64 + lane);
#pragma unroll
        for (int c = 0; c < 8; c++) {
            bf16x8 b = bp[c * 64];
            acc[c] = __builtin_amdgcn_mfma_f32_16x16x32_bf16(a, b, acc[c], 0, 0, 0);
        }
    }
    const int r0 = rowbase + (lane >> 4) * 4;
    const int col = lane & 15;
#pragma unroll
    for (int c = 0; c < 8; c++) {
#pragma unroll
        for (int r = 0; r < 4; r++) {
            int rr = r0 + r;
            if (rr < n) Y[(size_t)rr * 128 + c * 16 + col] = f2b(acc[c][r]);
        }
    }
}

// ---------------- pull aggregation (round-4 design) ----------------
// out[d] = dd*(sum_e dinv[s]*in[s] + dd*in[d]) + b; wave per dst row,
// lane covers bf16 cols {2l,2l+1} (one uint); 4-way unrolled gather.

template <int RELU, int SPLIT>
__global__ __launch_bounds__(256) void k_agg(const unsigned* __restrict__ in,
                                             const int* __restrict__ csr,
                                             const int* __restrict__ rowstart,
                                             const int* __restrict__ cnt,
                                             const float* __restrict__ dinv,
                                             const float* __restrict__ b0,
                                             const float* __restrict__ b1,
                                             void* __restrict__ out0v,
                                             void* __restrict__ out1v, int n) {
    const int wid = threadIdx.x >> 6;
    const int lane = threadIdx.x & 63;
    const int d = blockIdx.x * 4 + wid;
    if (d >= n) return;

    const float dd = dinv[d];
    unsigned su = in[(size_t)d * 64 + lane];
    float ax = dd * b_lo(su), ay = dd * b_hi(su);

    const int base = rowstart[d];
    const int m = cnt[d];
    int k = 0;
    for (; k + 3 < m; k += 4) {
        int s0 = csr[base + k];
        int s1 = csr[base + k + 1];
        int s2 = csr[base + k + 2];
        int s3 = csr[base + k + 3];
        float ds0 = dinv[s0], ds1 = dinv[s1], ds2 = dinv[s2], ds3 = dinv[s3];
        unsigned u0 = in[(size_t)s0 * 64 + lane];
        unsigned u1 = in[(size_t)s1 * 64 + lane];
        unsigned u2 = in[(size_t)s2 * 64 + lane];
        unsigned u3 = in[(size_t)s3 * 64 + lane];
        ax += ds0 * b_lo(u0) + ds1 * b_lo(u1) + ds2 * b_lo(u2) + ds3 * b_lo(u3);
        ay += ds0 * b_hi(u0) + ds1 * b_hi(u1) + ds2 * b_hi(u2) + ds3 * b_hi(u3);
    }
    for (; k < m; k++) {
        int s0 = csr[base + k];
        float ds0 = dinv[s0];
        unsigned u0 = in[(size_t)s0 * 64 + lane];
        ax += ds0 * b_lo(u0);
        ay += ds0 * b_hi(u0);
    }
    ax *= dd; ay *= dd;

    if (!SPLIT) {
        float2 b = reinterpret_cast<const float2*>(b0)[lane];
        ax += b.x; ay += b.y;
        if (RELU) { ax = fmaxf(ax, 0.f); ay = fmaxf(ay, 0.f); }
        ((unsigned*)out0v)[(size_t)d * 64 + lane] =
            (unsigned)f2b(ax) | ((unsigned)f2b(ay) << 16);
    } else {
        if (lane < 32) {
            float2 b = reinterpret_cast<const float2*>(b0)[lane];
            reinterpret_cast<float2*>(out0v)[(size_t)d * 32 + lane] =
                make_float2(ax + b.x, ay + b.y);
        } else {
            float2 b = reinterpret_cast<const float2*>(b1)[lane - 32];
            reinterpret_cast<float2*>(out1v)[(size_t)d * 32 + (lane - 32)] =
                make_float2(ax + b.x, ay + b.y);
        }
    }
}

// ---------------- launch ----------------

extern "C" void kernel_launch(void* const* d_in, const int* in_sizes, int n_in,
                              void* d_out, int out_size, void* d_ws, size_t ws_size,
                              hipStream_t stream) {
    const float* x    = (const float*)d_in[0];
    const float* W_h  = (const float*)d_in[1];
    const float* b_h  = (const float*)d_in[2];
    const float* W_mu = (const float*)d_in[3];
    const float* b_mu = (const float*)d_in[4];
    const float* W_ls = (const float*)d_in[5];
    const float* b_ls = (const float*)d_in[6];
    const int*   ei   = (const int*)d_in[7];

    const int E = in_sizes[7] / 2;
    const int n = in_sizes[0] / INC;  // 50000
    const int* src = ei;
    const int* dst = ei + E;
    float* out = (float*)d_out;

    char* p = (char*)d_ws;
    auto carve = [&](size_t bytes) {
        void* r = (void*)p;
        p += (bytes + 255) & ~(size_t)255;
        return r;
    };
    unsigned short* xw  = (unsigned short*)carve((size_t)n * HD * 2);   // gemm out (both layers)
    unsigned short* h   = (unsigned short*)carve((size_t)n * HD * 2);   // agg1 out
    unsigned short* wp1 = (unsigned short*)carve((size_t)INC * HD * 2);
    unsigned short* wp2 = (unsigned short*)carve((size_t)HD * HD * 2);
    float* dinv     = (float*)carve((size_t)n * 4);
    int*   cnt      = (int*)carve((size_t)n * 4);
    int*   rowstart = (int*)carve((size_t)n * 4);
    int*   part     = (int*)carve((size_t)SBS * 4);
    int*   bhist    = (int*)carve((size_t)NB * 4);
    int*   bbase    = (int*)carve((size_t)NB * 4);
    int*   bcur     = (int*)carve((size_t)NB * 4);
    unsigned* pairp = (unsigned*)carve((size_t)E * 4);
    int*   csr      = (int*)carve((size_t)E * 4);

    hipMemsetAsync(cnt, 0, (size_t)n * 4, stream);
    hipMemsetAsync(bhist, 0, (size_t)NB * 4, stream);

    const int nb = (n + SBS - 1) / SBS;
    k_count<<<(E + 255) / 256, 256, 0, stream>>>(dst, cnt, E);
    k_dinv<<<(n + 255) / 256, 256, 0, stream>>>(cnt, dinv, n);
    k_scan1<<<nb, SBS, 0, stream>>>(cnt, part, n);
    k_scan2<<<1, SBS, 0, stream>>>(part, nb);
    k_scan3<<<nb, SBS, 0, stream>>>(cnt, part, rowstart, n);
    k_bhist<<<256, 256, 0, stream>>>(dst, bhist, E);
    k_bscan<<<1, NB, 0, stream>>>(bhist, bbase, bcur);
    k_bscatter<<<(E + 1023) / 1024, 256, 0, stream>>>(src, dst, bcur, pairp, E);
    k_csr<<<NB, 256, 0, stream>>>(pairp, bbase, bhist, rowstart, csr, n);

    k_pack<INC, 0><<<INC * HD / 256, 256, 0, stream>>>(W_h, nullptr, wp1);
    k_pack<HD, 1><<<HD * HD / 256, 256, 0, stream>>>(W_mu, W_ls, wp2);

    k_mgemm<INC, 1><<<(n + 63) / 64, 256, 0, stream>>>(x, wp1, xw, n);
    k_agg<1, 0><<<(n + 3) / 4, 256, 0, stream>>>((const unsigned*)xw, csr, rowstart, cnt,
                                                 dinv, b_h, nullptr, h, nullptr, n);
    k_mgemm<HD, 0><<<(n + 63) / 64, 256, 0, stream>>>(h, wp2, xw, n);
    k_agg<0, 1><<<(n + 3) / 4, 256, 0, stream>>>((const unsigned*)xw, csr, rowstart, cnt,
                                                 dinv, b_mu, b_ls, out, out + (size_t)n * ZD, n);
}

// Round 11
// 347.216 us; speedup vs baseline: 7.1392x; 1.1796x over previous
//
#include <hip/hip_runtime.h>

#define INC 256
#define HD 128
#define ZD 64
#define SBS 256
#define NPB 196   // nodes per bucket
#define NB  256   // buckets = ceil(50000/196)

typedef __attribute__((ext_vector_type(8))) short bf16x8;
typedef __attribute__((ext_vector_type(4))) float f32x4;

static __device__ __forceinline__ unsigned short f2b(float f) {
    unsigned u = __builtin_bit_cast(unsigned, f);
    unsigned r = (u + 0x7fffu + ((u >> 16) & 1u)) >> 16;  // RNE
    return (unsigned short)r;
}
static __device__ __forceinline__ float b_lo(unsigned u) {
    return __builtin_bit_cast(float, u << 16);
}
static __device__ __forceinline__ float b_hi(unsigned u) {
    return __builtin_bit_cast(float, u & 0xffff0000u);
}

// ---------------- bucket histogram / scan / packed pair scatter ----------------

__global__ __launch_bounds__(256) void k_bhist(const int* __restrict__ dst,
                                               int* __restrict__ bhist, int E) {
    __shared__ int h[NB];
    h[threadIdx.x] = 0;
    __syncthreads();
    for (int i = blockIdx.x * blockDim.x + threadIdx.x; i < E; i += gridDim.x * blockDim.x)
        atomicAdd(&h[dst[i] / NPB], 1);
    __syncthreads();
    int v = h[threadIdx.x];
    if (v) atomicAdd(&bhist[threadIdx.x], v);
}

__global__ __launch_bounds__(NB) void k_bscan(const int* __restrict__ bhist,
                                              int* __restrict__ bbase,
                                              int* __restrict__ bcur) {
    __shared__ int s[NB];
    int t = threadIdx.x;
    int v = bhist[t];
    s[t] = v;
    __syncthreads();
    for (int o = 1; o < NB; o <<= 1) {
        int x = (t >= o) ? s[t - o] : 0;
        __syncthreads();
        s[t] += x;
        __syncthreads();
    }
    bbase[t] = s[t] - v;
    bcur[t] = s[t] - v;
}

// block handles 1024 edges; rank within bucket via LDS, reserve range, write
// packed (local_dst<<16 | src) -- valid because src < 50000 < 65536.
__global__ __launch_bounds__(256) void k_bscatter(const int* __restrict__ src,
                                                  const int* __restrict__ dst,
                                                  int* __restrict__ bcur,
                                                  unsigned* __restrict__ pairp, int E) {
    __shared__ int lcnt[NB];
    __shared__ int lbase[NB];
    const int t = threadIdx.x;
    lcnt[t] = 0;
    __syncthreads();
    const int c0 = blockIdx.x * 1024;
    unsigned u_[4]; int r_[4], b_[4], m_ = 0;
#pragma unroll
    for (int k = 0; k < 4; k++) {
        int i = c0 + k * 256 + t;
        if (i < E) {
            int dd = dst[i];
            int b = dd / NPB;
            b_[k] = b;
            u_[k] = (unsigned)src[i] | ((unsigned)(dd - b * NPB) << 16);
            r_[k] = atomicAdd(&lcnt[b], 1);
            m_ = k + 1;
        }
    }
    __syncthreads();
    lbase[t] = lcnt[t] ? atomicAdd(&bcur[t], lcnt[t]) : 0;
    __syncthreads();
    for (int k = 0; k < m_; k++)
        pairp[lbase[b_[k]] + r_[k]] = u_[k];
}

// ---------------- per-bucket degree count from pairp (replaces global-atomic k_count) ----
// LDS histogram of local_dst; coalesced cnt write. All n nodes covered.

__global__ __launch_bounds__(256) void k_bcount(const unsigned* __restrict__ pairp,
                                                const int* __restrict__ bbase,
                                                const int* __restrict__ bhist,
                                                int* __restrict__ cnt, int n) {
    __shared__ int lc[NPB];
    const int b = blockIdx.x;
    const int node0 = b * NPB;
    const int np = min(NPB, n - node0);
    for (int r = threadIdx.x; r < NPB; r += 256) lc[r] = 0;
    __syncthreads();
    const int lo = bbase[b], hi = lo + bhist[b];
    for (int i = lo + threadIdx.x; i < hi; i += 256)
        atomicAdd(&lc[pairp[i] >> 16], 1);
    __syncthreads();
    for (int r = threadIdx.x; r < np; r += 256) cnt[node0 + r] = lc[r];
}

__global__ void k_dinv(const int* __restrict__ cnt, float* __restrict__ dinv, int n) {
    int i = blockIdx.x * blockDim.x + threadIdx.x;
    if (i < n) dinv[i] = rsqrtf((float)(cnt[i] + 1));  // +1 self-loop
}

// ---------------- rowstart scan (3 kernels, cheap) ----------------

__global__ void k_scan1(const int* __restrict__ cnt, int* __restrict__ part, int n) {
    __shared__ int s[SBS];
    int i = blockIdx.x * SBS + threadIdx.x;
    s[threadIdx.x] = (i < n) ? cnt[i] : 0;
    __syncthreads();
    for (int o = SBS / 2; o > 0; o >>= 1) {
        if (threadIdx.x < o) s[threadIdx.x] += s[threadIdx.x + o];
        __syncthreads();
    }
    if (threadIdx.x == 0) part[blockIdx.x] = s[0];
}

__global__ void k_scan2(int* __restrict__ part, int nb) {
    __shared__ int s[SBS];
    int t = threadIdx.x;
    int v = (t < nb) ? part[t] : 0;
    s[t] = v;
    __syncthreads();
    for (int o = 1; o < SBS; o <<= 1) {
        int x = (t >= o) ? s[t - o] : 0;
        __syncthreads();
        s[t] += x;
        __syncthreads();
    }
    if (t < nb) part[t] = s[t] - v;  // exclusive
}

__global__ void k_scan3(const int* __restrict__ cnt, const int* __restrict__ part,
                        int* __restrict__ rowstart, int n) {
    __shared__ int s[SBS];
    int t = threadIdx.x;
    int i = blockIdx.x * SBS + t;
    int v = (i < n) ? cnt[i] : 0;
    s[t] = v;
    __syncthreads();
    for (int o = 1; o < SBS; o <<= 1) {
        int x = (t >= o) ? s[t - o] : 0;
        __syncthreads();
        s[t] += x;
        __syncthreads();
    }
    if (i < n) rowstart[i] = part[blockIdx.x] + s[t] - v;
}

// per-bucket exact-CSR placement; write window = bucket's 25KB CSR slice (L2-combined)
__global__ __launch_bounds__(256) void k_csr(const unsigned* __restrict__ pairp,
                                             const int* __restrict__ bbase,
                                             const int* __restrict__ bhist,
                                             const int* __restrict__ rowstart,
                                             int* __restrict__ csr, int n) {
    __shared__ int cur[NPB];
    const int b = blockIdx.x;
    const int node0 = b * NPB;
    const int np = min(NPB, n - node0);
    for (int r = threadIdx.x; r < np; r += 256) cur[r] = rowstart[node0 + r];
    __syncthreads();
    const int lo = bbase[b], hi = lo + bhist[b];
    for (int i = lo + threadIdx.x; i < hi; i += 256) {
        unsigned u = pairp[i];
        int p = atomicAdd(&cur[u >> 16], 1);
        csr[p] = (int)(u & 0xffffu);
    }
}

// ---------------- W pack: [K][128] f32 -> MFMA B-fragment-major bf16 ----------

template <int K, int SPLITB>
__global__ void k_pack(const float* __restrict__ Wa, const float* __restrict__ Wb,
                       unsigned short* __restrict__ Wp) {
    int idx = blockIdx.x * 256 + threadIdx.x;  // < K*128
    int j = idx & 7, lane = (idx >> 3) & 63, c = (idx >> 9) & 7, s = idx >> 12;
    int k = s * 32 + (lane >> 4) * 8 + j;
    int col = c * 16 + (lane & 15);
    float v;
    if (!SPLITB) v = Wa[k * 128 + col];
    else v = (col < 64) ? Wa[k * 64 + col] : Wb[k * 64 + (col - 64)];
    Wp[idx] = f2b(v);
}

// ---------------- MFMA GEMM: Y[n,128](bf16) = A[n,K] @ Wp ----------------

template <int K, int AF32>
__global__ __launch_bounds__(256) void k_mgemm(const void* __restrict__ Av,
                                               const unsigned short* __restrict__ Wp,
                                               unsigned short* __restrict__ Y, int n) {
    const int lane = threadIdx.x & 63;
    const int w = threadIdx.x >> 6;
    const int rowbase = blockIdx.x * 64 + w * 16;
    int arow = rowbase + (lane & 15);
    if (arow >= n) arow = n - 1;  // clamp; stores are guarded
    const int kgrp = lane >> 4;

    f32x4 acc[8] = {};
#pragma unroll
    for (int s = 0; s < K / 32; s++) {
        bf16x8 a;
        if (AF32) {
            const float* ap = (const float*)Av + (size_t)arow * K + s * 32 + kgrp * 8;
            float4 f0 = *reinterpret_cast<const float4*>(ap);
            float4 f1 = *reinterpret_cast<const float4*>(ap + 4);
            a[0] = (short)f2b(f0.x); a[1] = (short)f2b(f0.y);
            a[2] = (short)f2b(f0.z); a[3] = (short)f2b(f0.w);
            a[4] = (short)f2b(f1.x); a[5] = (short)f2b(f1.y);
            a[6] = (short)f2b(f1.z); a[7] = (short)f2b(f1.w);
        } else {
            a = *reinterpret_cast<const bf16x8*>((const unsigned short*)Av +
                                                 (size_t)arow * K + s * 32 + kgrp * 8);
        }
        const bf16x8* bp = reinterpret_cast<const bf16x8*>(Wp) + ((size_t)s * 8 * 64 + lane);
#pragma unroll
        for (int c = 0; c < 8; c++) {
            bf16x8 b = bp[c * 64];
            acc[c] = __builtin_amdgcn_mfma_f32_16x16x32_bf16(a, b, acc[c], 0, 0, 0);
        }
    }
    const int r0 = rowbase + (lane >> 4) * 4;
    const int col = lane & 15;
#pragma unroll
    for (int c = 0; c < 8; c++) {
#pragma unroll
        for (int r = 0; r < 4; r++) {
            int rr = r0 + r;
            if (rr < n) Y[(size_t)rr * 128 + c * 16 + col] = f2b(acc[c][r]);
        }
    }
}

// ---------------- pull aggregation ----------------
// out[d] = dd*(sum_e dinv[s]*in[s] + dd*in[d]) + b; wave per dst row,
// lane covers bf16 cols {2l,2l+1} (one uint); 4-way unrolled gather.

template <int RELU, int SPLIT>
__global__ __launch_bounds__(256) void k_agg(const unsigned* __restrict__ in,
                                             const int* __restrict__ csr,
                                             const int* __restrict__ rowstart,
                                             const int* __restrict__ cnt,
                                             const float* __restrict__ dinv,
                                             const float* __restrict__ b0,
                                             const float* __restrict__ b1,
                                             void* __restrict__ out0v,
                                             void* __restrict__ out1v, int n) {
    const int wid = threadIdx.x >> 6;
    const int lane = threadIdx.x & 63;
    const int d = blockIdx.x * 4 + wid;
    if (d >= n) return;

    const float dd = dinv[d];
    unsigned su = in[(size_t)d * 64 + lane];
    float ax = dd * b_lo(su), ay = dd * b_hi(su);

    const int base = rowstart[d];
    const int m = cnt[d];
    int k = 0;
    for (; k + 3 < m; k += 4) {
        int s0 = csr[base + k];
        int s1 = csr[base + k + 1];
        int s2 = csr[base + k + 2];
        int s3 = csr[base + k + 3];
        float ds0 = dinv[s0], ds1 = dinv[s1], ds2 = dinv[s2], ds3 = dinv[s3];
        unsigned u0 = in[(size_t)s0 * 64 + lane];
        unsigned u1 = in[(size_t)s1 * 64 + lane];
        unsigned u2 = in[(size_t)s2 * 64 + lane];
        unsigned u3 = in[(size_t)s3 * 64 + lane];
        ax += ds0 * b_lo(u0) + ds1 * b_lo(u1) + ds2 * b_lo(u2) + ds3 * b_lo(u3);
        ay += ds0 * b_hi(u0) + ds1 * b_hi(u1) + ds2 * b_hi(u2) + ds3 * b_hi(u3);
    }
    for (; k < m; k++) {
        int s0 = csr[base + k];
        float ds0 = dinv[s0];
        unsigned u0 = in[(size_t)s0 * 64 + lane];
        ax += ds0 * b_lo(u0);
        ay += ds0 * b_hi(u0);
    }
    ax *= dd; ay *= dd;

    if (!SPLIT) {
        float2 b = reinterpret_cast<const float2*>(b0)[lane];
        ax += b.x; ay += b.y;
        if (RELU) { ax = fmaxf(ax, 0.f); ay = fmaxf(ay, 0.f); }
        ((unsigned*)out0v)[(size_t)d * 64 + lane] =
            (unsigned)f2b(ax) | ((unsigned)f2b(ay) << 16);
    } else {
        if (lane < 32) {
            float2 b = reinterpret_cast<const float2*>(b0)[lane];
            reinterpret_cast<float2*>(out0v)[(size_t)d * 32 + lane] =
                make_float2(ax + b.x, ay + b.y);
        } else {
            float2 b = reinterpret_cast<const float2*>(b1)[lane - 32];
            reinterpret_cast<float2*>(out1v)[(size_t)d * 32 + (lane - 32)] =
                make_float2(ax + b.x, ay + b.y);
        }
    }
}

// ---------------- launch ----------------

extern "C" void kernel_launch(void* const* d_in, const int* in_sizes, int n_in,
                              void* d_out, int out_size, void* d_ws, size_t ws_size,
                              hipStream_t stream) {
    const float* x    = (const float*)d_in[0];
    const float* W_h  = (const float*)d_in[1];
    const float* b_h  = (const float*)d_in[2];
    const float* W_mu = (const float*)d_in[3];
    const float* b_mu = (const float*)d_in[4];
    const float* W_ls = (const float*)d_in[5];
    const float* b_ls = (const float*)d_in[6];
    const int*   ei   = (const int*)d_in[7];

    const int E = in_sizes[7] / 2;
    const int n = in_sizes[0] / INC;  // 50000
    const int* src = ei;
    const int* dst = ei + E;
    float* out = (float*)d_out;

    char* p = (char*)d_ws;
    auto carve = [&](size_t bytes) {
        void* r = (void*)p;
        p += (bytes + 255) & ~(size_t)255;
        return r;
    };
    unsigned short* xw  = (unsigned short*)carve((size_t)n * HD * 2);   // gemm out (both layers)
    unsigned short* h   = (unsigned short*)carve((size_t)n * HD * 2);   // agg1 out
    unsigned short* wp1 = (unsigned short*)carve((size_t)INC * HD * 2);
    unsigned short* wp2 = (unsigned short*)carve((size_t)HD * HD * 2);
    float* dinv     = (float*)carve((size_t)n * 4);
    int*   cnt      = (int*)carve((size_t)n * 4);
    int*   rowstart = (int*)carve((size_t)n * 4);
    int*   part     = (int*)carve((size_t)SBS * 4);
    int*   bhist    = (int*)carve((size_t)NB * 4);
    int*   bbase    = (int*)carve((size_t)NB * 4);
    int*   bcur     = (int*)carve((size_t)NB * 4);
    unsigned* pairp = (unsigned*)carve((size_t)E * 4);
    int*   csr      = (int*)carve((size_t)E * 4);

    hipMemsetAsync(bhist, 0, (size_t)NB * 4, stream);

    const int nb = (n + SBS - 1) / SBS;
    k_bhist<<<256, 256, 0, stream>>>(dst, bhist, E);
    k_bscan<<<1, NB, 0, stream>>>(bhist, bbase, bcur);
    k_bscatter<<<(E + 1023) / 1024, 256, 0, stream>>>(src, dst, bcur, pairp, E);
    k_bcount<<<NB, 256, 0, stream>>>(pairp, bbase, bhist, cnt, n);
    k_dinv<<<(n + 255) / 256, 256, 0, stream>>>(cnt, dinv, n);
    k_scan1<<<nb, SBS, 0, stream>>>(cnt, part, n);
    k_scan2<<<1, SBS, 0, stream>>>(part, nb);
    k_scan3<<<nb, SBS, 0, stream>>>(cnt, part, rowstart, n);
    k_csr<<<NB, 256, 0, stream>>>(pairp, bbase, bhist, rowstart, csr, n);

    k_pack<INC, 0><<<INC * HD / 256, 256, 0, stream>>>(W_h, nullptr, wp1);
    k_pack<HD, 1><<<HD * HD / 256, 256, 0, stream>>>(W_mu, W_ls, wp2);

    k_mgemm<INC, 1><<<(n + 63) / 64, 256, 0, stream>>>(x, wp1, xw, n);
    k_agg<1, 0><<<(n + 3) / 4, 256, 0, stream>>>((const unsigned*)xw, csr, rowstart, cnt,
                                                 dinv, b_h, nullptr, h, nullptr, n);
    k_mgemm<HD, 0><<<(n + 63) / 64, 256, 0, stream>>>(h, wp2, xw, n);
    k_agg<0, 1><<<(n + 3) / 4, 256, 0, stream>>>((const unsigned*)xw, csr, rowstart, cnt,
                                                 dinv, b_mu, b_ls, out, out + (size_t)n * ZD, n);
}

// Round 13
// 318.601 us; speedup vs baseline: 7.7804x; 1.0898x over previous
//
#include <hip/hip_runtime.h>

#define INC 256
#define HD 128
#define ZD 64
#define NPB 196   // nodes per bucket
#define NB  256   // buckets = ceil(50000/196)

typedef __attribute__((ext_vector_type(8))) short bf16x8;
typedef __attribute__((ext_vector_type(4))) float f32x4;

static __device__ __forceinline__ unsigned short f2b(float f) {
    unsigned u = __builtin_bit_cast(unsigned, f);
    unsigned r = (u + 0x7fffu + ((u >> 16) & 1u)) >> 16;  // RNE
    return (unsigned short)r;
}
static __device__ __forceinline__ float b_lo(unsigned u) {
    return __builtin_bit_cast(float, u << 16);
}
static __device__ __forceinline__ float b_hi(unsigned u) {
    return __builtin_bit_cast(float, u & 0xffff0000u);
}

// ---------------- bucket histogram / scan / packed pair scatter ----------------

__global__ __launch_bounds__(256) void k_bhist(const int* __restrict__ dst,
                                               int* __restrict__ bhist, int E) {
    __shared__ int h[NB];
    h[threadIdx.x] = 0;
    __syncthreads();
    for (int i = blockIdx.x * blockDim.x + threadIdx.x; i < E; i += gridDim.x * blockDim.x)
        atomicAdd(&h[dst[i] / NPB], 1);
    __syncthreads();
    int v = h[threadIdx.x];
    if (v) atomicAdd(&bhist[threadIdx.x], v);
}

__global__ __launch_bounds__(NB) void k_bscan(const int* __restrict__ bhist,
                                              int* __restrict__ bbase,
                                              int* __restrict__ bcur) {
    __shared__ int s[NB];
    int t = threadIdx.x;
    int v = bhist[t];
    s[t] = v;
    __syncthreads();
    for (int o = 1; o < NB; o <<= 1) {
        int x = (t >= o) ? s[t - o] : 0;
        __syncthreads();
        s[t] += x;
        __syncthreads();
    }
    bbase[t] = s[t] - v;
    bcur[t] = s[t] - v;
}

// block handles 1024 edges; rank within bucket via LDS, reserve range, write
// packed (local_dst<<16 | src) -- valid because src < 50000 < 65536.
__global__ __launch_bounds__(256) void k_bscatter(const int* __restrict__ src,
                                                  const int* __restrict__ dst,
                                                  int* __restrict__ bcur,
                                                  unsigned* __restrict__ pairp, int E) {
    __shared__ int lcnt[NB];
    __shared__ int lbase[NB];
    const int t = threadIdx.x;
    lcnt[t] = 0;
    __syncthreads();
    const int c0 = blockIdx.x * 1024;
    unsigned u_[4]; int r_[4], b_[4], m_ = 0;
#pragma unroll
    for (int k = 0; k < 4; k++) {
        int i = c0 + k * 256 + t;
        if (i < E) {
            int dd = dst[i];
            int b = dd / NPB;
            b_[k] = b;
            u_[k] = (unsigned)src[i] | ((unsigned)(dd - b * NPB) << 16);
            r_[k] = atomicAdd(&lcnt[b], 1);
            m_ = k + 1;
        }
    }
    __syncthreads();
    lbase[t] = lcnt[t] ? atomicAdd(&bcur[t], lcnt[t]) : 0;
    __syncthreads();
    for (int k = 0; k < m_; k++)
        pairp[lbase[b_[k]] + r_[k]] = u_[k];
}

// ---------------- fused per-bucket build: cnt + dinv + rowstart + CSR ----------
// CSR is bucket-major: bucket b owns csr[bbase[b] .. bbase[b]+bhist[b]);
// rowstart[node] = bbase[b] + local_exclusive_scan(lc). Replaces the global
// scan chain (k_bcount, k_dinv, k_scan1-3, k_csr).

__global__ __launch_bounds__(256) void k_build(const unsigned* __restrict__ pairp,
                                               const int* __restrict__ bbase,
                                               const int* __restrict__ bhist,
                                               int* __restrict__ cnt,
                                               float* __restrict__ dinv,
                                               int* __restrict__ rowstart,
                                               int* __restrict__ csr, int n) {
    __shared__ int lc[NPB];
    __shared__ int cur[NPB];
    __shared__ int s[256];
    const int t = threadIdx.x;
    const int b = blockIdx.x;
    const int node0 = b * NPB;
    const int np = min(NPB, n - node0);

    for (int r = t; r < NPB; r += 256) lc[r] = 0;
    __syncthreads();
    const int lo = bbase[b], hi = lo + bhist[b];
    for (int i = lo + t; i < hi; i += 256)
        atomicAdd(&lc[pairp[i] >> 16], 1);
    __syncthreads();

    int v = (t < NPB) ? lc[t] : 0;
    s[t] = v;
    __syncthreads();
    for (int o = 1; o < 256; o <<= 1) {
        int x = (t >= o) ? s[t - o] : 0;
        __syncthreads();
        s[t] += x;
        __syncthreads();
    }
    if (t < np) {
        int rs = lo + s[t] - v;  // exclusive scan + bucket base
        rowstart[node0 + t] = rs;
        cnt[node0 + t] = v;
        dinv[node0 + t] = rsqrtf((float)(v + 1));  // +1 self-loop
        cur[t] = rs;
    }
    __syncthreads();
    for (int i = lo + t; i < hi; i += 256) {
        unsigned u = pairp[i];
        int p = atomicAdd(&cur[u >> 16], 1);
        csr[p] = (int)(u & 0xffffu);
    }
}

// ---------------- W pack: [K][128] f32 -> MFMA B-fragment-major bf16 ----------

template <int K, int SPLITB>
__global__ void k_pack(const float* __restrict__ Wa, const float* __restrict__ Wb,
                       unsigned short* __restrict__ Wp) {
    int idx = blockIdx.x * 256 + threadIdx.x;  // < K*128
    int j = idx & 7, lane = (idx >> 3) & 63, c = (idx >> 9) & 7, s = idx >> 12;
    int k = s * 32 + (lane >> 4) * 8 + j;
    int col = c * 16 + (lane & 15);
    float v;
    if (!SPLITB) v = Wa[k * 128 + col];
    else v = (col < 64) ? Wa[k * 64 + col] : Wb[k * 64 + (col - 64)];
    Wp[idx] = f2b(v);
}

// ---------------- MFMA GEMM: Y[n,128](bf16) = A[n,K] @ Wp ----------------

template <int K, int AF32>
__global__ __launch_bounds__(256) void k_mgemm(const void* __restrict__ Av,
                                               const unsigned short* __restrict__ Wp,
                                               unsigned short* __restrict__ Y, int n) {
    const int lane = threadIdx.x & 63;
    const int w = threadIdx.x >> 6;
    const int rowbase = blockIdx.x * 64 + w * 16;
    int arow = rowbase + (lane & 15);
    if (arow >= n) arow = n - 1;  // clamp; stores are guarded
    const int kgrp = lane >> 4;

    f32x4 acc[8] = {};
#pragma unroll
    for (int s = 0; s < K / 32; s++) {
        bf16x8 a;
        if (AF32) {
            const float* ap = (const float*)Av + (size_t)arow * K + s * 32 + kgrp * 8;
            float4 f0 = *reinterpret_cast<const float4*>(ap);
            float4 f1 = *reinterpret_cast<const float4*>(ap + 4);
            a[0] = (short)f2b(f0.x); a[1] = (short)f2b(f0.y);
            a[2] = (short)f2b(f0.z); a[3] = (short)f2b(f0.w);
            a[4] = (short)f2b(f1.x); a[5] = (short)f2b(f1.y);
            a[6] = (short)f2b(f1.z); a[7] = (short)f2b(f1.w);
        } else {
            a = *reinterpret_cast<const bf16x8*>((const unsigned short*)Av +
                                                 (size_t)arow * K + s * 32 + kgrp * 8);
        }
        const bf16x8* bp = reinterpret_cast<const bf16x8*>(Wp) + ((size_t)s * 8 * 64 + lane);
#pragma unroll
        for (int c = 0; c < 8; c++) {
            bf16x8 b = bp[c * 64];
            acc[c] = __builtin_amdgcn_mfma_f32_16x16x32_bf16(a, b, acc[c], 0, 0, 0);
        }
    }
    const int r0 = rowbase + (lane >> 4) * 4;
    const int col = lane & 15;
#pragma unroll
    for (int c = 0; c < 8; c++) {
#pragma unroll
        for (int r = 0; r < 4; r++) {
            int rr = r0 + r;
            if (rr < n) Y[(size_t)rr * 128 + c * 16 + col] = f2b(acc[c][r]);
        }
    }
}

// ---------------- pull aggregation ----------------
// out[d] = dd*(sum_e dinv[s]*in[s] + dd*in[d]) + b; wave per dst row,
// lane covers bf16 cols {2l,2l+1} (one uint); 8-way unrolled gather for MLP
// (csr/dinv loads are wave-uniform -> scalarized; 8 outstanding 256B gathers).

#define EDGE(i) \
    { int s##i = csr[base + k + i]; \
      float ds = dinv[s##i]; \
      unsigned u = in[(size_t)s##i * 64 + lane]; \
      ax += ds * b_lo(u); ay += ds * b_hi(u); }

template <int RELU, int SPLIT>
__global__ __launch_bounds__(256) void k_agg(const unsigned* __restrict__ in,
                                             const int* __restrict__ csr,
                                             const int* __restrict__ rowstart,
                                             const int* __restrict__ cnt,
                                             const float* __restrict__ dinv,
                                             const float* __restrict__ b0,
                                             const float* __restrict__ b1,
                                             void* __restrict__ out0v,
                                             void* __restrict__ out1v, int n) {
    const int wid = threadIdx.x >> 6;
    const int lane = threadIdx.x & 63;
    const int d = blockIdx.x * 4 + wid;
    if (d >= n) return;

    const float dd = dinv[d];
    unsigned su = in[(size_t)d * 64 + lane];
    float ax = dd * b_lo(su), ay = dd * b_hi(su);

    const int base = rowstart[d];
    const int m = cnt[d];
    int k = 0;
    for (; k + 7 < m; k += 8) {
        int s0 = csr[base + k],     s1 = csr[base + k + 1];
        int s2 = csr[base + k + 2], s3 = csr[base + k + 3];
        int s4 = csr[base + k + 4], s5 = csr[base + k + 5];
        int s6 = csr[base + k + 6], s7 = csr[base + k + 7];
        float e0 = dinv[s0], e1 = dinv[s1], e2 = dinv[s2], e3 = dinv[s3];
        float e4 = dinv[s4], e5 = dinv[s5], e6 = dinv[s6], e7 = dinv[s7];
        unsigned u0 = in[(size_t)s0 * 64 + lane];
        unsigned u1 = in[(size_t)s1 * 64 + lane];
        unsigned u2 = in[(size_t)s2 * 64 + lane];
        unsigned u3 = in[(size_t)s3 * 64 + lane];
        unsigned u4 = in[(size_t)s4 * 64 + lane];
        unsigned u5 = in[(size_t)s5 * 64 + lane];
        unsigned u6 = in[(size_t)s6 * 64 + lane];
        unsigned u7 = in[(size_t)s7 * 64 + lane];
        ax += e0 * b_lo(u0) + e1 * b_lo(u1) + e2 * b_lo(u2) + e3 * b_lo(u3)
            + e4 * b_lo(u4) + e5 * b_lo(u5) + e6 * b_lo(u6) + e7 * b_lo(u7);
        ay += e0 * b_hi(u0) + e1 * b_hi(u1) + e2 * b_hi(u2) + e3 * b_hi(u3)
            + e4 * b_hi(u4) + e5 * b_hi(u5) + e6 * b_hi(u6) + e7 * b_hi(u7);
    }
    for (; k + 3 < m; k += 4) {
        int s0 = csr[base + k],     s1 = csr[base + k + 1];
        int s2 = csr[base + k + 2], s3 = csr[base + k + 3];
        float e0 = dinv[s0], e1 = dinv[s1], e2 = dinv[s2], e3 = dinv[s3];
        unsigned u0 = in[(size_t)s0 * 64 + lane];
        unsigned u1 = in[(size_t)s1 * 64 + lane];
        unsigned u2 = in[(size_t)s2 * 64 + lane];
        unsigned u3 = in[(size_t)s3 * 64 + lane];
        ax += e0 * b_lo(u0) + e1 * b_lo(u1) + e2 * b_lo(u2) + e3 * b_lo(u3);
        ay += e0 * b_hi(u0) + e1 * b_hi(u1) + e2 * b_hi(u2) + e3 * b_hi(u3);
    }
    for (; k < m; k++) EDGE(0);
    ax *= dd; ay *= dd;

    if (!SPLIT) {
        float2 b = reinterpret_cast<const float2*>(b0)[lane];
        ax += b.x; ay += b.y;
        if (RELU) { ax = fmaxf(ax, 0.f); ay = fmaxf(ay, 0.f); }
        ((unsigned*)out0v)[(size_t)d * 64 + lane] =
            (unsigned)f2b(ax) | ((unsigned)f2b(ay) << 16);
    } else {
        if (lane < 32) {
            float2 b = reinterpret_cast<const float2*>(b0)[lane];
            reinterpret_cast<float2*>(out0v)[(size_t)d * 32 + lane] =
                make_float2(ax + b.x, ay + b.y);
        } else {
            float2 b = reinterpret_cast<const float2*>(b1)[lane - 32];
            reinterpret_cast<float2*>(out1v)[(size_t)d * 32 + (lane - 32)] =
                make_float2(ax + b.x, ay + b.y);
        }
    }
}

// ---------------- launch ----------------

extern "C" void kernel_launch(void* const* d_in, const int* in_sizes, int n_in,
                              void* d_out, int out_size, void* d_ws, size_t ws_size,
                              hipStream_t stream) {
    const float* x    = (const float*)d_in[0];
    const float* W_h  = (const float*)d_in[1];
    const float* b_h  = (const float*)d_in[2];
    const float* W_mu = (const float*)d_in[3];
    const float* b_mu = (const float*)d_in[4];
    const float* W_ls = (const float*)d_in[5];
    const float* b_ls = (const float*)d_in[6];
    const int*   ei   = (const int*)d_in[7];

    const int E = in_sizes[7] / 2;
    const int n = in_sizes[0] / INC;  // 50000
    const int* src = ei;
    const int* dst = ei + E;
    float* out = (float*)d_out;

    char* p = (char*)d_ws;
    auto carve = [&](size_t bytes) {
        void* r = (void*)p;
        p += (bytes + 255) & ~(size_t)255;
        return r;
    };
    unsigned short* xw  = (unsigned short*)carve((size_t)n * HD * 2);   // gemm out (both layers)
    unsigned short* h   = (unsigned short*)carve((size_t)n * HD * 2);   // agg1 out
    unsigned short* wp1 = (unsigned short*)carve((size_t)INC * HD * 2);
    unsigned short* wp2 = (unsigned short*)carve((size_t)HD * HD * 2);
    float* dinv     = (float*)carve((size_t)n * 4);
    int*   cnt      = (int*)carve((size_t)n * 4);
    int*   rowstart = (int*)carve((size_t)n * 4);
    int*   bhist    = (int*)carve((size_t)NB * 4);
    int*   bbase    = (int*)carve((size_t)NB * 4);
    int*   bcur     = (int*)carve((size_t)NB * 4);
    unsigned* pairp = (unsigned*)carve((size_t)E * 4);
    int*   csr      = (int*)carve((size_t)E * 4);

    hipMemsetAsync(bhist, 0, (size_t)NB * 4, stream);

    k_bhist<<<256, 256, 0, stream>>>(dst, bhist, E);
    k_bscan<<<1, NB, 0, stream>>>(bhist, bbase, bcur);
    k_bscatter<<<(E + 1023) / 1024, 256, 0, stream>>>(src, dst, bcur, pairp, E);
    k_build<<<NB, 256, 0, stream>>>(pairp, bbase, bhist, cnt, dinv, rowstart, csr, n);

    k_pack<INC, 0><<<INC * HD / 256, 256, 0, stream>>>(W_h, nullptr, wp1);
    k_pack<HD, 1><<<HD * HD / 256, 256, 0, stream>>>(W_mu, W_ls, wp2);

    k_mgemm<INC, 1><<<(n + 63) / 64, 256, 0, stream>>>(x, wp1, xw, n);
    k_agg<1, 0><<<(n + 3) / 4, 256, 0, stream>>>((const unsigned*)xw, csr, rowstart, cnt,
                                                 dinv, b_h, nullptr, h, nullptr, n);
    k_mgemm<HD, 0><<<(n + 63) / 64, 256, 0, stream>>>(h, wp2, xw, n);
    k_agg<0, 1><<<(n + 3) / 4, 256, 0, stream>>>((const unsigned*)xw, csr, rowstart, cnt,
                                                 dinv, b_mu, b_ls, out, out + (size_t)n * ZD, n);
}

// Round 14
// 310.389 us; speedup vs baseline: 7.9863x; 1.0265x over previous
//
#include <hip/hip_runtime.h>

#define INC 256
#define HD 128
#define ZD 64
#define NPB 196   // nodes per bucket
#define NB  256   // buckets = ceil(50000/196)

typedef __attribute__((ext_vector_type(8))) short bf16x8;
typedef __attribute__((ext_vector_type(4))) float f32x4;

static __device__ __forceinline__ unsigned short f2b(float f) {
    unsigned u = __builtin_bit_cast(unsigned, f);
    unsigned r = (u + 0x7fffu + ((u >> 16) & 1u)) >> 16;  // RNE
    return (unsigned short)r;
}
static __device__ __forceinline__ float b_lo(unsigned u) {
    return __builtin_bit_cast(float, u << 16);
}
static __device__ __forceinline__ float b_hi(unsigned u) {
    return __builtin_bit_cast(float, u & 0xffff0000u);
}

// ---------------- bucket histogram / scan / packed pair scatter ----------------

__global__ __launch_bounds__(256) void k_bhist(const int* __restrict__ dst,
                                               int* __restrict__ bhist, int E) {
    __shared__ int h[NB];
    h[threadIdx.x] = 0;
    __syncthreads();
    for (int i = blockIdx.x * blockDim.x + threadIdx.x; i < E; i += gridDim.x * blockDim.x)
        atomicAdd(&h[dst[i] / NPB], 1);
    __syncthreads();
    int v = h[threadIdx.x];
    if (v) atomicAdd(&bhist[threadIdx.x], v);
}

__global__ __launch_bounds__(NB) void k_bscan(const int* __restrict__ bhist,
                                              int* __restrict__ bbase,
                                              int* __restrict__ bcur) {
    __shared__ int s[NB];
    int t = threadIdx.x;
    int v = bhist[t];
    s[t] = v;
    __syncthreads();
    for (int o = 1; o < NB; o <<= 1) {
        int x = (t >= o) ? s[t - o] : 0;
        __syncthreads();
        s[t] += x;
        __syncthreads();
    }
    bbase[t] = s[t] - v;
    bcur[t] = s[t] - v;
}

// block handles 1024 edges; rank within bucket via LDS, reserve range, write
// packed (local_dst<<16 | src) -- valid because src < 50000 < 65536.
__global__ __launch_bounds__(256) void k_bscatter(const int* __restrict__ src,
                                                  const int* __restrict__ dst,
                                                  int* __restrict__ bcur,
                                                  unsigned* __restrict__ pairp, int E) {
    __shared__ int lcnt[NB];
    __shared__ int lbase[NB];
    const int t = threadIdx.x;
    lcnt[t] = 0;
    __syncthreads();
    const int c0 = blockIdx.x * 1024;
    unsigned u_[4]; int r_[4], b_[4], m_ = 0;
#pragma unroll
    for (int k = 0; k < 4; k++) {
        int i = c0 + k * 256 + t;
        if (i < E) {
            int dd = dst[i];
            int b = dd / NPB;
            b_[k] = b;
            u_[k] = (unsigned)src[i] | ((unsigned)(dd - b * NPB) << 16);
            r_[k] = atomicAdd(&lcnt[b], 1);
            m_ = k + 1;
        }
    }
    __syncthreads();
    lbase[t] = lcnt[t] ? atomicAdd(&bcur[t], lcnt[t]) : 0;
    __syncthreads();
    for (int k = 0; k < m_; k++)
        pairp[lbase[b_[k]] + r_[k]] = u_[k];
}

// ---------------- fused per-bucket build: cnt + dinv + rowstart + CSR ----------
// CSR holds BYTE OFFSETS (src*256) for direct scalar-base gathers in k_agg.

__global__ __launch_bounds__(256) void k_build(const unsigned* __restrict__ pairp,
                                               const int* __restrict__ bbase,
                                               const int* __restrict__ bhist,
                                               int* __restrict__ cnt,
                                               float* __restrict__ dinv,
                                               int* __restrict__ rowstart,
                                               unsigned* __restrict__ csr, int n) {
    __shared__ int lc[NPB];
    __shared__ int cur[NPB];
    __shared__ int s[256];
    const int t = threadIdx.x;
    const int b = blockIdx.x;
    const int node0 = b * NPB;
    const int np = min(NPB, n - node0);

    for (int r = t; r < NPB; r += 256) lc[r] = 0;
    __syncthreads();
    const int lo = bbase[b], hi = lo + bhist[b];
    for (int i = lo + t; i < hi; i += 256)
        atomicAdd(&lc[pairp[i] >> 16], 1);
    __syncthreads();

    int v = (t < NPB) ? lc[t] : 0;
    s[t] = v;
    __syncthreads();
    for (int o = 1; o < 256; o <<= 1) {
        int x = (t >= o) ? s[t - o] : 0;
        __syncthreads();
        s[t] += x;
        __syncthreads();
    }
    if (t < np) {
        int rs = lo + s[t] - v;  // exclusive scan + bucket base
        rowstart[node0 + t] = rs;
        cnt[node0 + t] = v;
        dinv[node0 + t] = rsqrtf((float)(v + 1));  // +1 self-loop
        cur[t] = rs;
    }
    __syncthreads();
    for (int i = lo + t; i < hi; i += 256) {
        unsigned u = pairp[i];
        int p = atomicAdd(&cur[u >> 16], 1);
        csr[p] = (u & 0xffffu) << 8;  // src * 256B row stride
    }
}

// ---------------- W pack: [K][128] f32 -> MFMA B-fragment-major bf16 ----------

template <int K, int SPLITB>
__global__ void k_pack(const float* __restrict__ Wa, const float* __restrict__ Wb,
                       unsigned short* __restrict__ Wp) {
    int idx = blockIdx.x * 256 + threadIdx.x;  // < K*128
    int j = idx & 7, lane = (idx >> 3) & 63, c = (idx >> 9) & 7, s = idx >> 12;
    int k = s * 32 + (lane >> 4) * 8 + j;
    int col = c * 16 + (lane & 15);
    float v;
    if (!SPLITB) v = Wa[k * 128 + col];
    else v = (col < 64) ? Wa[k * 64 + col] : Wb[k * 64 + (col - 64)];
    Wp[idx] = f2b(v);
}

// ---------------- MFMA GEMM: Y[n,128](bf16) = rowscale[n] * (A[n,K] @ Wp) -----
// Row-scaling fused in epilogue: output rows pre-multiplied by dinv so the
// aggregation needs NO per-edge scale (out[d] = dd*(sum xs[s] + xs[d]) + b).

template <int K, int AF32>
__global__ __launch_bounds__(256) void k_mgemm(const void* __restrict__ Av,
                                               const unsigned short* __restrict__ Wp,
                                               const float* __restrict__ rowscale,
                                               unsigned short* __restrict__ Y, int n) {
    const int lane = threadIdx.x & 63;
    const int w = threadIdx.x >> 6;
    const int rowbase = blockIdx.x * 64 + w * 16;
    int arow = rowbase + (lane & 15);
    if (arow >= n) arow = n - 1;  // clamp; stores are guarded
    const int kgrp = lane >> 4;

    f32x4 acc[8] = {};
#pragma unroll
    for (int s = 0; s < K / 32; s++) {
        bf16x8 a;
        if (AF32) {
            const float* ap = (const float*)Av + (size_t)arow * K + s * 32 + kgrp * 8;
            float4 f0 = *reinterpret_cast<const float4*>(ap);
            float4 f1 = *reinterpret_cast<const float4*>(ap + 4);
            a[0] = (short)f2b(f0.x); a[1] = (short)f2b(f0.y);
            a[2] = (short)f2b(f0.z); a[3] = (short)f2b(f0.w);
            a[4] = (short)f2b(f1.x); a[5] = (short)f2b(f1.y);
            a[6] = (short)f2b(f1.z); a[7] = (short)f2b(f1.w);
        } else {
            a = *reinterpret_cast<const bf16x8*>((const unsigned short*)Av +
                                                 (size_t)arow * K + s * 32 + kgrp * 8);
        }
        const bf16x8* bp = reinterpret_cast<const bf16x8*>(Wp) + ((size_t)s * 8 * 64 + lane);
#pragma unroll
        for (int c = 0; c < 8; c++) {
            bf16x8 b = bp[c * 64];
            acc[c] = __builtin_amdgcn_mfma_f32_16x16x32_bf16(a, b, acc[c], 0, 0, 0);
        }
    }
    const int r0 = rowbase + (lane >> 4) * 4;
    const int col = lane & 15;
    float sc[4];
#pragma unroll
    for (int r = 0; r < 4; r++) {
        int rr = r0 + r;
        sc[r] = (rr < n) ? rowscale[rr] : 0.f;
    }
#pragma unroll
    for (int c = 0; c < 8; c++) {
#pragma unroll
        for (int r = 0; r < 4; r++) {
            int rr = r0 + r;
            if (rr < n) Y[(size_t)rr * 128 + c * 16 + col] = f2b(acc[c][r] * sc[r]);
        }
    }
}

// ---------------- pull aggregation (pre-scaled input) ----------------
// out[d] = dd*(sum_e xs[s] + xs[d]) + b, xs pre-scaled by dinv in GEMM epilogue.
// csr holds byte offsets; readfirstlane -> scalar-base gathers (no per-edge
// VALU addressing, no per-edge scale). 16 outstanding 256B gathers per wave.

template <int RELU, int SPLIT>
__global__ __launch_bounds__(256) void k_agg(const unsigned* __restrict__ in,
                                             const unsigned* __restrict__ csr,
                                             const int* __restrict__ rowstart,
                                             const int* __restrict__ cnt,
                                             const float* __restrict__ dinv,
                                             const float* __restrict__ b0,
                                             const float* __restrict__ b1,
                                             void* __restrict__ out0v,
                                             void* __restrict__ out1v, int n) {
    const int wid = threadIdx.x >> 6;
    const int lane = threadIdx.x & 63;
    const int d = blockIdx.x * 4 + wid;
    if (d >= n) return;

    const float dd = dinv[d];
    unsigned su = in[(size_t)d * 64 + lane];
    float ax = b_lo(su), ay = b_hi(su);  // self term (already dinv-scaled)

    const int base = __builtin_amdgcn_readfirstlane(rowstart[d]);
    const int m = __builtin_amdgcn_readfirstlane(cnt[d]);
    const char* inb = (const char*)in;
    const int l4 = lane << 2;

    int k = 0;
    for (; k + 15 < m; k += 16) {
        unsigned u[16];
#pragma unroll
        for (int j = 0; j < 16; j++) {
            unsigned off = (unsigned)__builtin_amdgcn_readfirstlane((int)csr[base + k + j]);
            u[j] = *reinterpret_cast<const unsigned*>(inb + off + l4);
        }
#pragma unroll
        for (int j = 0; j < 16; j++) { ax += b_lo(u[j]); ay += b_hi(u[j]); }
    }
    for (; k + 3 < m; k += 4) {
        unsigned u[4];
#pragma unroll
        for (int j = 0; j < 4; j++) {
            unsigned off = (unsigned)__builtin_amdgcn_readfirstlane((int)csr[base + k + j]);
            u[j] = *reinterpret_cast<const unsigned*>(inb + off + l4);
        }
#pragma unroll
        for (int j = 0; j < 4; j++) { ax += b_lo(u[j]); ay += b_hi(u[j]); }
    }
    for (; k < m; k++) {
        unsigned off = (unsigned)__builtin_amdgcn_readfirstlane((int)csr[base + k]);
        unsigned u = *reinterpret_cast<const unsigned*>(inb + off + l4);
        ax += b_lo(u); ay += b_hi(u);
    }
    ax *= dd; ay *= dd;

    if (!SPLIT) {
        float2 b = reinterpret_cast<const float2*>(b0)[lane];
        ax += b.x; ay += b.y;
        if (RELU) { ax = fmaxf(ax, 0.f); ay = fmaxf(ay, 0.f); }
        ((unsigned*)out0v)[(size_t)d * 64 + lane] =
            (unsigned)f2b(ax) | ((unsigned)f2b(ay) << 16);
    } else {
        if (lane < 32) {
            float2 b = reinterpret_cast<const float2*>(b0)[lane];
            reinterpret_cast<float2*>(out0v)[(size_t)d * 32 + lane] =
                make_float2(ax + b.x, ay + b.y);
        } else {
            float2 b = reinterpret_cast<const float2*>(b1)[lane - 32];
            reinterpret_cast<float2*>(out1v)[(size_t)d * 32 + (lane - 32)] =
                make_float2(ax + b.x, ay + b.y);
        }
    }
}

// ---------------- launch ----------------

extern "C" void kernel_launch(void* const* d_in, const int* in_sizes, int n_in,
                              void* d_out, int out_size, void* d_ws, size_t ws_size,
                              hipStream_t stream) {
    const float* x    = (const float*)d_in[0];
    const float* W_h  = (const float*)d_in[1];
    const float* b_h  = (const float*)d_in[2];
    const float* W_mu = (const float*)d_in[3];
    const float* b_mu = (const float*)d_in[4];
    const float* W_ls = (const float*)d_in[5];
    const float* b_ls = (const float*)d_in[6];
    const int*   ei   = (const int*)d_in[7];

    const int E = in_sizes[7] / 2;
    const int n = in_sizes[0] / INC;  // 50000
    const int* src = ei;
    const int* dst = ei + E;
    float* out = (float*)d_out;

    char* p = (char*)d_ws;
    auto carve = [&](size_t bytes) {
        void* r = (void*)p;
        p += (bytes + 255) & ~(size_t)255;
        return r;
    };
    unsigned short* xw  = (unsigned short*)carve((size_t)n * HD * 2);   // scaled gemm out (both layers)
    unsigned short* h   = (unsigned short*)carve((size_t)n * HD * 2);   // agg1 out (unscaled)
    unsigned short* wp1 = (unsigned short*)carve((size_t)INC * HD * 2);
    unsigned short* wp2 = (unsigned short*)carve((size_t)HD * HD * 2);
    float* dinv     = (float*)carve((size_t)n * 4);
    int*   cnt      = (int*)carve((size_t)n * 4);
    int*   rowstart = (int*)carve((size_t)n * 4);
    int*   bhist    = (int*)carve((size_t)NB * 4);
    int*   bbase    = (int*)carve((size_t)NB * 4);
    int*   bcur     = (int*)carve((size_t)NB * 4);
    unsigned* pairp = (unsigned*)carve((size_t)E * 4);
    unsigned* csr   = (unsigned*)carve((size_t)E * 4);

    hipMemsetAsync(bhist, 0, (size_t)NB * 4, stream);

    k_bhist<<<256, 256, 0, stream>>>(dst, bhist, E);
    k_bscan<<<1, NB, 0, stream>>>(bhist, bbase, bcur);
    k_bscatter<<<(E + 1023) / 1024, 256, 0, stream>>>(src, dst, bcur, pairp, E);
    k_build<<<NB, 256, 0, stream>>>(pairp, bbase, bhist, cnt, dinv, rowstart, csr, n);

    k_pack<INC, 0><<<INC * HD / 256, 256, 0, stream>>>(W_h, nullptr, wp1);
    k_pack<HD, 1><<<HD * HD / 256, 256, 0, stream>>>(W_mu, W_ls, wp2);

    k_mgemm<INC, 1><<<(n + 63) / 64, 256, 0, stream>>>(x, wp1, dinv, xw, n);
    k_agg<1, 0><<<(n + 3) / 4, 256, 0, stream>>>((const unsigned*)xw, csr, rowstart, cnt,
                                                 dinv, b_h, nullptr, h, nullptr, n);
    k_mgemm<HD, 0><<<(n + 63) / 64, 256, 0, stream>>>(h, wp2, dinv, xw, n);
    k_agg<0, 1><<<(n + 3) / 4, 256, 0, stream>>>((const unsigned*)xw, csr, rowstart, cnt,
                                                 dinv, b_mu, b_ls, out, out + (size_t)n * ZD, n);
}